// Round 6
// baseline (409.362 us; speedup 1.0000x reference)
//
#include <hip/hip_runtime.h>
#include <hip/hip_fp16.h>
#include <hip/hip_cooperative_groups.h>

namespace cg = cooperative_groups;

#define N_NODES 50000
#define N_EDGES 800000
#define D 64

#define SLICES 100                 // edge slices per role
#define I4S    2000                // int4 per slice (8000 edges)
#define NI4    200000              // total int4 per role
#define NWORDS 12512               // ceil(50000/4) padded to /4
#define GRID   1024                // coop grid: 4 blocks/CU x 256 CUs

typedef float vfloat4 __attribute__((ext_vector_type(4)));

// ---------------------------------------------------------------------------
// Workspace layout (bytes), ~21.2 MB, offsets 256-aligned:
//   [0,        64)         ctr    : int (scan counter; zeroed by degree pass)
//   [256,      200256)     base   : int[N_NODES]
//   [200320,   400320)     rend   : int[N_NODES]
//   [400384,   600384)     snorm  : float[N_NODES]
//   [600448,   800448)     dnorm  : float[N_NODES]
//   [800512,   4000512)    ssrc   : int[N_EDGES]  src ids grouped by dst
//   [4000768,  4800768)    occ    : uchar[N_EDGES] within-slice occurrence
//   [4800768,  14810368)   partial: uint[200][NWORDS] byte hists -> prefixes
//   [14810368, 21210368)   y16    : half[N_NODES*D]
// ---------------------------------------------------------------------------
#define CTR_OFF    0
#define BASE_OFF   256
#define END_OFF    200320
#define SNORM_OFF  400384
#define DNORM_OFF  600448
#define SSRC_OFF   800512
#define OCC_OFF    4000768
#define PART_OFF   4800768
#define Y16_OFF    14810368

// ---------------------------------------------------------------------------
// Pass 1: per-slice byte-packed degree histograms in LDS. dst-role blocks also
// record each edge's within-slice occurrence byte (atomicAdd return) -> occ[].
// Block b: role = b&1 (0=src/outdeg, 1=dst/indeg), slice = b>>1.
// Block 0 zeroes the scan counter (no memset dispatch).
// ---------------------------------------------------------------------------
__global__ __launch_bounds__(256) void degree_occ_kernel(const int4* __restrict__ src4,
                                                         const int4* __restrict__ dst4,
                                                         unsigned int* __restrict__ partial,
                                                         uchar4* __restrict__ occ4,
                                                         int* __restrict__ ctr) {
    __shared__ unsigned int hist[NWORDS];
    int tid = threadIdx.x;
    if (blockIdx.x == 0 && tid == 0) *ctr = 0;
    uint4* h4 = (uint4*)hist;
    for (int i = tid; i < NWORDS / 4; i += 256) h4[i] = make_uint4(0, 0, 0, 0);
    __syncthreads();

    int role  = blockIdx.x & 1;
    int slice = blockIdx.x >> 1;
    int beg = slice * I4S, end = beg + I4S;
    if (role == 0) {
        for (int i = beg + tid; i < end; i += 256) {
            int4 v = src4[i];
            atomicAdd(&hist[v.x >> 2], 1u << ((v.x & 3) * 8));
            atomicAdd(&hist[v.y >> 2], 1u << ((v.y & 3) * 8));
            atomicAdd(&hist[v.z >> 2], 1u << ((v.z & 3) * 8));
            atomicAdd(&hist[v.w >> 2], 1u << ((v.w & 3) * 8));
        }
    } else {
        for (int i = beg + tid; i < end; i += 256) {
            int4 v = dst4[i];
            unsigned int o0 = (atomicAdd(&hist[v.x >> 2], 1u << ((v.x & 3) * 8)) >> ((v.x & 3) * 8)) & 0xFFu;
            unsigned int o1 = (atomicAdd(&hist[v.y >> 2], 1u << ((v.y & 3) * 8)) >> ((v.y & 3) * 8)) & 0xFFu;
            unsigned int o2 = (atomicAdd(&hist[v.z >> 2], 1u << ((v.z & 3) * 8)) >> ((v.z & 3) * 8)) & 0xFFu;
            unsigned int o3 = (atomicAdd(&hist[v.w >> 2], 1u << ((v.w & 3) * 8)) >> ((v.w & 3) * 8)) & 0xFFu;
            occ4[i] = make_uchar4((unsigned char)o0, (unsigned char)o1,
                                  (unsigned char)o2, (unsigned char)o3);
        }
    }
    __syncthreads();

    uint4* p4 = (uint4*)(partial + (size_t)blockIdx.x * NWORDS);
    for (int i = tid; i < NWORDS / 4; i += 256) p4[i] = h4[i];
}

// --------------------------- phase bodies ----------------------------------

// Merge + scan: thread per word (4 nodes). Sums packed degrees over slices,
// rewrites dst-role partials in place to per-slice EXCLUSIVE prefixes
// (byte adds; cumulative <= indeg < 255), wave-scans for CSR bases.
__device__ __forceinline__ void phase_merge(unsigned int* __restrict__ partial,
                                            int* __restrict__ base,
                                            int* __restrict__ rend,
                                            float* __restrict__ snorm,
                                            float* __restrict__ dnorm,
                                            int* __restrict__ ctr,
                                            int tid, int lane) {
    int w = tid;
    unsigned int accin = 0, accout = 0;
    bool act = (w < 12500);
    if (act) {
        unsigned int* po = partial + w;            // src role at slot 2s
        unsigned int* pd = partial + NWORDS + w;   // dst role at slot 2s+1
#pragma unroll 4
        for (int s = 0; s < SLICES; s++) {
            size_t off = (size_t)(2 * s) * NWORDS;
            accout += po[off];
            unsigned int v = pd[off];
            pd[off] = accin;                       // exclusive prefix
            accin += v;
        }
    }
    int d0 = accin & 0xFF, d1 = (accin >> 8) & 0xFF,
        d2 = (accin >> 16) & 0xFF, d3 = (accin >> 24) & 0xFF;
    int tsum = d0 + d1 + d2 + d3;
    int run = tsum;
#pragma unroll
    for (int off = 1; off < 64; off <<= 1) {
        int v = __shfl_up(run, off);
        if (lane >= off) run += v;
    }
    int wtot = __shfl(run, 63);
    int wbase = 0;
    if (lane == 63 && wtot != 0) wbase = atomicAdd(ctr, wtot);
    wbase = __shfl(wbase, 63);
    if (act) {
        int b0 = wbase + run - tsum;
        int b1 = b0 + d0, b2 = b1 + d1, b3 = b2 + d2;
        ((int4*)base)[w] = make_int4(b0, b1, b2, b3);
        ((int4*)rend)[w] = make_int4(b1, b2, b3, b3 + d3);
        ((float4*)dnorm)[w] = make_float4(rsqrtf(fmaxf((float)d0, 1.f)),
                                          rsqrtf(fmaxf((float)d1, 1.f)),
                                          rsqrtf(fmaxf((float)d2, 1.f)),
                                          rsqrtf(fmaxf((float)d3, 1.f)));
        int o0 = accout & 0xFF, o1 = (accout >> 8) & 0xFF,
            o2 = (accout >> 16) & 0xFF, o3 = (accout >> 24) & 0xFF;
        ((float4*)snorm)[w] = make_float4(rsqrtf(fmaxf((float)o0, 1.f)),
                                          rsqrtf(fmaxf((float)o1, 1.f)),
                                          rsqrtf(fmaxf((float)o2, 1.f)),
                                          rsqrtf(fmaxf((float)o3, 1.f)));
    }
}

// CSR fill, fully parallel, no LDS: p = base[t] + slice-prefix byte + occ byte.
__device__ __forceinline__ void phase_fill(const int4* __restrict__ src4,
                                           const int4* __restrict__ dst4,
                                           const uchar4* __restrict__ occ4,
                                           const unsigned int* __restrict__ partial,
                                           const int* __restrict__ base,
                                           int* __restrict__ ssrc,
                                           int tid) {
    if (tid < NI4) {
        int s = tid / I4S;
        const unsigned int* pref = partial + (size_t)(2 * s + 1) * NWORDS;
        int4 sv = src4[tid], tv = dst4[tid];
        uchar4 oc = occ4[tid];
#define FILL_ONE(T, S, O)                                                     \
        {                                                                     \
            int t = (T); int sh = (t & 3) * 8;                                \
            int p = base[t] + (int)((pref[t >> 2] >> sh) & 0xFFu) + (int)(O); \
            ssrc[p] = (S);                                                    \
        }
        FILL_ONE(tv.x, sv.x, oc.x)
        FILL_ONE(tv.y, sv.y, oc.y)
        FILL_ONE(tv.z, sv.z, oc.z)
        FILL_ONE(tv.w, sv.w, oc.w)
#undef FILL_ONE
    }
}

// y = (x * snorm) @ W, stored fp16. Wave per node; W one column per lane.
__device__ __forceinline__ void phase_y(const float* __restrict__ x,
                                        const float* __restrict__ snorm,
                                        const float* __restrict__ W,
                                        __half* __restrict__ y16,
                                        int tid, int lane, int nwaves) {
    float Wreg[D];
#pragma unroll
    for (int k = 0; k < D; k++) Wreg[k] = W[k * D + lane];
    int wave = tid >> 6;
    for (int n = wave; n < N_NODES; n += nwaves) {
        float hv = x[(size_t)n * D + lane] * snorm[n];
        int hb = __float_as_int(hv);
        float p0 = 0.f, p1 = 0.f, p2 = 0.f, p3 = 0.f;
#pragma unroll
        for (int k = 0; k < D; k += 4) {
            p0 = fmaf(__int_as_float(__builtin_amdgcn_readlane(hb, k + 0)), Wreg[k + 0], p0);
            p1 = fmaf(__int_as_float(__builtin_amdgcn_readlane(hb, k + 1)), Wreg[k + 1], p1);
            p2 = fmaf(__int_as_float(__builtin_amdgcn_readlane(hb, k + 2)), Wreg[k + 2], p2);
            p3 = fmaf(__int_as_float(__builtin_amdgcn_readlane(hb, k + 3)), Wreg[k + 3], p3);
        }
        y16[(size_t)n * D + lane] = __float2half((p0 + p1) + (p2 + p3));
    }
}

// Gather: wave per node. lane = (quad = edge-in-group-of-4, c = half4 chunk);
// one 8B load covers 1/4 row -> one wave-load = 4 rows; 8-deep pipeline = 32
// edges in flight. Combine via shfl(lane^16), shfl(lane^32); quad 0 writes
// coalesced nontemporal float4.
__device__ __forceinline__ void phase_gather(const __half* __restrict__ y16,
                                             const int* __restrict__ ssrc,
                                             const int* __restrict__ base,
                                             const int* __restrict__ rend,
                                             const float* __restrict__ dnorm,
                                             const float* __restrict__ bias,
                                             float* __restrict__ out,
                                             int tid, int lane, int nwaves) {
    int quad = lane >> 4;
    int c    = lane & 15;
    int wave = tid >> 6;
    float4 b4 = ((const float4*)bias)[c];
    const uint2* ycol = (const uint2*)y16 + c;   // row stride = 16 uint2

#define ACC(A, V)                                                             \
    {                                                                         \
        __half2 h01 = *(__half2*)&(V).x; __half2 h23 = *(__half2*)&(V).y;     \
        float2 f01 = __half22float2(h01); float2 f23 = __half22float2(h23);   \
        (A).x += f01.x; (A).y += f01.y; (A).z += f23.x; (A).w += f23.y;       \
    }

    for (int n = wave; n < N_NODES; n += nwaves) {
        int beg = base[n], end = rend[n];
        float4 a0 = make_float4(0, 0, 0, 0), a1 = a0, a2 = a0, a3 = a0;
        float4 a4 = a0, a5 = a0, a6 = a0, a7 = a0;
        int i = beg;
        for (; i + 32 <= end; i += 32) {       // 32 edges, 8 loads in flight
            int s0 = ssrc[i + quad],      s1 = ssrc[i + 4 + quad];
            int s2 = ssrc[i + 8 + quad],  s3 = ssrc[i + 12 + quad];
            int s4 = ssrc[i + 16 + quad], s5 = ssrc[i + 20 + quad];
            int s6 = ssrc[i + 24 + quad], s7 = ssrc[i + 28 + quad];
            uint2 v0 = ycol[(size_t)s0 * 16];
            uint2 v1 = ycol[(size_t)s1 * 16];
            uint2 v2 = ycol[(size_t)s2 * 16];
            uint2 v3 = ycol[(size_t)s3 * 16];
            uint2 v4 = ycol[(size_t)s4 * 16];
            uint2 v5 = ycol[(size_t)s5 * 16];
            uint2 v6 = ycol[(size_t)s6 * 16];
            uint2 v7 = ycol[(size_t)s7 * 16];
            ACC(a0, v0) ACC(a1, v1) ACC(a2, v2) ACC(a3, v3)
            ACC(a4, v4) ACC(a5, v5) ACC(a6, v6) ACC(a7, v7)
        }
        for (; i + 4 <= end; i += 4) {
            int s = ssrc[i + quad];
            uint2 v = ycol[(size_t)s * 16];
            ACC(a0, v)
        }
        if (i + quad < end) {                  // tail < 4 edges
            int s = ssrc[i + quad];
            uint2 v = ycol[(size_t)s * 16];
            ACC(a1, v)
        }
        float4 t;
        t.x = ((a0.x + a1.x) + (a2.x + a3.x)) + ((a4.x + a5.x) + (a6.x + a7.x));
        t.y = ((a0.y + a1.y) + (a2.y + a3.y)) + ((a4.y + a5.y) + (a6.y + a7.y));
        t.z = ((a0.z + a1.z) + (a2.z + a3.z)) + ((a4.z + a5.z) + (a6.z + a7.z));
        t.w = ((a0.w + a1.w) + (a2.w + a3.w)) + ((a4.w + a5.w) + (a6.w + a7.w));
        t.x += __shfl(t.x, lane ^ 16); t.y += __shfl(t.y, lane ^ 16);
        t.z += __shfl(t.z, lane ^ 16); t.w += __shfl(t.w, lane ^ 16);
        t.x += __shfl(t.x, lane ^ 32); t.y += __shfl(t.y, lane ^ 32);
        t.z += __shfl(t.z, lane ^ 32); t.w += __shfl(t.w, lane ^ 32);
        if (quad == 0) {
            float dn = dnorm[n];
            vfloat4 o;
            o.x = fmaf(t.x, dn, b4.x);
            o.y = fmaf(t.y, dn, b4.y);
            o.z = fmaf(t.z, dn, b4.z);
            o.w = fmaf(t.w, dn, b4.w);
            __builtin_nontemporal_store(o, (vfloat4*)(out + (size_t)n * D) + c);
        }
    }
#undef ACC
}

// ------------------- cooperative mega-kernel (2nd dispatch) -----------------
__global__ __launch_bounds__(256, 4) void coop_kernel(const int4* src4, const int4* dst4,
                                                      unsigned int* partial, const uchar4* occ4,
                                                      int* base, int* rend,
                                                      float* snorm, float* dnorm, int* ctr,
                                                      int* ssrc, const float* x, const float* W,
                                                      __half* y16, const float* bias, float* out) {
    cg::grid_group grid = cg::this_grid();
    int tid = blockIdx.x * blockDim.x + threadIdx.x;
    int lane = threadIdx.x & 63;
    int nwaves = (gridDim.x * blockDim.x) >> 6;

    phase_merge(partial, base, rend, snorm, dnorm, ctr, tid, lane);
    grid.sync();
    phase_fill(src4, dst4, occ4, partial, base, ssrc, tid);
    phase_y(x, snorm, W, y16, tid, lane, nwaves);
    grid.sync();
    phase_gather(y16, ssrc, base, rend, dnorm, bias, out, tid, lane, nwaves);
}

// ------------------- fallback (if cooperative launch unsupported) -----------
__global__ __launch_bounds__(256, 4) void merge_fb(unsigned int* partial, int* base, int* rend,
                                                   float* snorm, float* dnorm, int* ctr) {
    int tid = blockIdx.x * blockDim.x + threadIdx.x;
    phase_merge(partial, base, rend, snorm, dnorm, ctr, tid, threadIdx.x & 63);
}
__global__ __launch_bounds__(256, 4) void filly_fb(const int4* src4, const int4* dst4,
                                                   const uchar4* occ4, unsigned int* partial,
                                                   int* base, int* ssrc, const float* x,
                                                   const float* snorm, const float* W, __half* y16) {
    int tid = blockIdx.x * blockDim.x + threadIdx.x;
    int nwaves = (gridDim.x * blockDim.x) >> 6;
    phase_fill(src4, dst4, occ4, partial, base, ssrc, tid);
    phase_y(x, snorm, W, y16, tid, threadIdx.x & 63, nwaves);
}
__global__ __launch_bounds__(256, 4) void gather_fb(const __half* y16, const int* ssrc,
                                                    const int* base, const int* rend,
                                                    const float* dnorm, const float* bias,
                                                    float* out) {
    int tid = blockIdx.x * blockDim.x + threadIdx.x;
    int nwaves = (gridDim.x * blockDim.x) >> 6;
    phase_gather(y16, ssrc, base, rend, dnorm, bias, out, tid, threadIdx.x & 63, nwaves);
}

extern "C" void kernel_launch(void* const* d_in, const int* in_sizes, int n_in,
                              void* d_out, int out_size, void* d_ws, size_t ws_size,
                              hipStream_t stream) {
    const float* x   = (const float*)d_in[0];
    const int*   src = (const int*)d_in[1];
    const int*   dst = (const int*)d_in[2];
    const float* W   = (const float*)d_in[3];
    const float* b   = (const float*)d_in[4];
    float* out = (float*)d_out;

    char* ws = (char*)d_ws;
    int*          ctr   = (int*)(ws + CTR_OFF);
    int*          base  = (int*)(ws + BASE_OFF);
    int*          rend  = (int*)(ws + END_OFF);
    float*        snorm = (float*)(ws + SNORM_OFF);
    float*        dnorm = (float*)(ws + DNORM_OFF);
    int*          ssrc  = (int*)(ws + SSRC_OFF);
    uchar4*       occ4  = (uchar4*)(ws + OCC_OFF);
    unsigned int* part  = (unsigned int*)(ws + PART_OFF);
    __half*       y16   = (__half*)(ws + Y16_OFF);

    const int4* src4 = (const int4*)src;
    const int4* dst4 = (const int4*)dst;

    degree_occ_kernel<<<2 * SLICES, 256, 0, stream>>>(src4, dst4, part, occ4, ctr);

    void* args[] = {(void*)&src4, (void*)&dst4, (void*)&part, (void*)&occ4,
                    (void*)&base, (void*)&rend, (void*)&snorm, (void*)&dnorm,
                    (void*)&ctr, (void*)&ssrc, (void*)&x, (void*)&W,
                    (void*)&y16, (void*)&b, (void*)&out};
    hipError_t e = hipLaunchCooperativeKernel((const void*)coop_kernel,
                                              dim3(GRID), dim3(256), args, 0, stream);
    if (e != hipSuccess) {
        // Fallback: same phase code as 3 ordinary dispatches.
        merge_fb<<<GRID, 256, 0, stream>>>(part, base, rend, snorm, dnorm, ctr);
        filly_fb<<<GRID, 256, 0, stream>>>(src4, dst4, occ4, part, base, ssrc,
                                           x, snorm, W, y16);
        gather_fb<<<GRID, 256, 0, stream>>>(y16, ssrc, base, rend, dnorm, b, out);
    }
}

// Round 7
// 151.460 us; speedup vs baseline: 2.7028x; 2.7028x over previous
//
#include <hip/hip_runtime.h>
#include <hip/hip_fp16.h>

#define N_NODES 50000
#define N_EDGES 800000
#define D 64

#define SLICES 100                 // edge slices per role (src/dst)
#define I4S    2000                // int4 per slice (8000 edges)
#define NI4    200000              // total int4 per role
#define NWORDS 12512               // ceil(50000/4)=12500, padded to /4

typedef float vfloat2 __attribute__((ext_vector_type(2)));

// ---------------------------------------------------------------------------
// Workspace layout (bytes), ~21.2 MB, offsets 256-aligned:
//   [0,        64)         ctr    : int (scan counter; zeroed by degree pass)
//   [256,      200256)     base   : int[N_NODES]
//   [200320,   400320)     rend   : int[N_NODES]
//   [400384,   600384)     snorm  : float[N_NODES]
//   [600448,   800448)     dnorm  : float[N_NODES]
//   [800512,   4000512)    ssrc   : int[N_EDGES]   src ids grouped by dst
//   [4000768,  4800768)    occ    : uchar[N_EDGES] within-slice occurrence
//   [4800768,  14810368)   partial: uint[200][NWORDS] byte hists -> prefixes
//   [14810368, 21210368)   y16    : half[N_NODES*D]
// ---------------------------------------------------------------------------
#define CTR_OFF    0
#define BASE_OFF   256
#define END_OFF    200320
#define SNORM_OFF  400384
#define DNORM_OFF  600448
#define SSRC_OFF   800512
#define OCC_OFF    4000768
#define PART_OFF   4800768
#define Y16_OFF    14810368

// ---------------------------------------------------------------------------
// Pass 1: per-slice byte-packed degree histograms in LDS (no fabric atomics).
// dst-role blocks also record each edge's within-slice occurrence byte
// (the atomicAdd return) into occ[] so the fill pass needs no histogram.
// Block b: role = b&1 (0=src/outdeg, 1=dst/indeg), slice = b>>1.
// Block 0 zeroes the scan counter (replaces the memset dispatch).
// ---------------------------------------------------------------------------
__global__ __launch_bounds__(256) void degree_occ_kernel(const int4* __restrict__ src4,
                                                         const int4* __restrict__ dst4,
                                                         unsigned int* __restrict__ partial,
                                                         uchar4* __restrict__ occ4,
                                                         int* __restrict__ ctr) {
    __shared__ unsigned int hist[NWORDS];
    int tid = threadIdx.x;
    if (blockIdx.x == 0 && tid == 0) *ctr = 0;
    uint4* h4 = (uint4*)hist;
    for (int i = tid; i < NWORDS / 4; i += 256) h4[i] = make_uint4(0, 0, 0, 0);
    __syncthreads();

    int role  = blockIdx.x & 1;
    int slice = blockIdx.x >> 1;
    int beg = slice * I4S, end = beg + I4S;
    if (role == 0) {
        for (int i = beg + tid; i < end; i += 256) {
            int4 v = src4[i];
            atomicAdd(&hist[v.x >> 2], 1u << ((v.x & 3) * 8));
            atomicAdd(&hist[v.y >> 2], 1u << ((v.y & 3) * 8));
            atomicAdd(&hist[v.z >> 2], 1u << ((v.z & 3) * 8));
            atomicAdd(&hist[v.w >> 2], 1u << ((v.w & 3) * 8));
        }
    } else {
        for (int i = beg + tid; i < end; i += 256) {
            int4 v = dst4[i];
            unsigned int o0 = (atomicAdd(&hist[v.x >> 2], 1u << ((v.x & 3) * 8)) >> ((v.x & 3) * 8)) & 0xFFu;
            unsigned int o1 = (atomicAdd(&hist[v.y >> 2], 1u << ((v.y & 3) * 8)) >> ((v.y & 3) * 8)) & 0xFFu;
            unsigned int o2 = (atomicAdd(&hist[v.z >> 2], 1u << ((v.z & 3) * 8)) >> ((v.z & 3) * 8)) & 0xFFu;
            unsigned int o3 = (atomicAdd(&hist[v.w >> 2], 1u << ((v.w & 3) * 8)) >> ((v.w & 3) * 8)) & 0xFFu;
            occ4[i] = make_uchar4((unsigned char)o0, (unsigned char)o1,
                                  (unsigned char)o2, (unsigned char)o3);
        }
    }
    __syncthreads();

    uint4* p4 = (uint4*)(partial + (size_t)blockIdx.x * NWORDS);
    for (int i = tid; i < NWORDS / 4; i += 256) p4[i] = h4[i];
}

// Pass 2 (fused merge + scan): thread per word (4 nodes). Sums packed degrees
// over all slices, rewrites dst-role partials in place to per-slice EXCLUSIVE
// prefixes (byte adds; cumulative <= indeg < 255, no carry), then wave-scans
// the 4-node sums for CSR bases; writes node arrays as int4/float4.
__global__ __launch_bounds__(256) void merge_scan_kernel(unsigned int* __restrict__ partial,
                                                         int* __restrict__ base,
                                                         int* __restrict__ rend,
                                                         float* __restrict__ snorm,
                                                         float* __restrict__ dnorm,
                                                         int* __restrict__ ctr) {
    int w = blockIdx.x * blockDim.x + threadIdx.x;
    int lane = threadIdx.x & 63;
    unsigned int accin = 0, accout = 0;
    if (w < 12500) {
        unsigned int* po = partial + w;            // src role: slot 2s
        unsigned int* pd = partial + NWORDS + w;   // dst role: slot 2s+1
#pragma unroll 4
        for (int s = 0; s < SLICES; s++) {
            size_t off = (size_t)(2 * s) * NWORDS;
            accout += po[off];
            unsigned int v = pd[off];
            pd[off] = accin;                       // exclusive prefix before slice s
            accin += v;
        }
    }
    int d0 = accin & 0xFF, d1 = (accin >> 8) & 0xFF,
        d2 = (accin >> 16) & 0xFF, d3 = (accin >> 24) & 0xFF;
    int tsum = d0 + d1 + d2 + d3;
    int run = tsum;  // inclusive wave scan of per-thread totals
#pragma unroll
    for (int off = 1; off < 64; off <<= 1) {
        int v = __shfl_up(run, off);
        if (lane >= off) run += v;
    }
    int wtot = __shfl(run, 63);
    int wbase = 0;
    if (lane == 63) wbase = atomicAdd(ctr, wtot);
    wbase = __shfl(wbase, 63);
    if (w < 12500) {
        int b0 = wbase + run - tsum;
        int b1 = b0 + d0, b2 = b1 + d1, b3 = b2 + d2;
        ((int4*)base)[w] = make_int4(b0, b1, b2, b3);
        ((int4*)rend)[w] = make_int4(b1, b2, b3, b3 + d3);
        ((float4*)dnorm)[w] = make_float4(rsqrtf(fmaxf((float)d0, 1.f)),
                                          rsqrtf(fmaxf((float)d1, 1.f)),
                                          rsqrtf(fmaxf((float)d2, 1.f)),
                                          rsqrtf(fmaxf((float)d3, 1.f)));
        int o0 = accout & 0xFF, o1 = (accout >> 8) & 0xFF,
            o2 = (accout >> 16) & 0xFF, o3 = (accout >> 24) & 0xFF;
        ((float4*)snorm)[w] = make_float4(rsqrtf(fmaxf((float)o0, 1.f)),
                                          rsqrtf(fmaxf((float)o1, 1.f)),
                                          rsqrtf(fmaxf((float)o2, 1.f)),
                                          rsqrtf(fmaxf((float)o3, 1.f)));
    }
}

// Pass 3 (fused fill + y): two independent streaming phases in one dispatch.
// Fill: fully parallel, no LDS, no atomics — p = base[t] + slice prefix + occ.
// Y:    y = (x * snorm) @ W stored fp16; wave per node, W one column per lane.
#define FYBLK 1024
__global__ __launch_bounds__(256, 4) void filly_kernel(const int4* __restrict__ src4,
                                                       const int4* __restrict__ dst4,
                                                       const uchar4* __restrict__ occ4,
                                                       const unsigned int* __restrict__ partial,
                                                       const int* __restrict__ base,
                                                       int* __restrict__ ssrc,
                                                       const float* __restrict__ x,
                                                       const float* __restrict__ snorm,
                                                       const float* __restrict__ W,
                                                       __half* __restrict__ y16) {
    int tid = blockIdx.x * blockDim.x + threadIdx.x;
    int lane = threadIdx.x & 63;

    if (tid < NI4) {
        int s = tid / I4S;
        const unsigned int* pref = partial + (size_t)(2 * s + 1) * NWORDS;
        int4 sv = src4[tid], tv = dst4[tid];
        uchar4 oc = occ4[tid];
#define FILL_ONE(T, S, O)                                                     \
        {                                                                     \
            int t = (T); int sh = (t & 3) * 8;                                \
            int p = base[t] + (int)((pref[t >> 2] >> sh) & 0xFFu) + (int)(O); \
            ssrc[p] = (S);                                                    \
        }
        FILL_ONE(tv.x, sv.x, oc.x)
        FILL_ONE(tv.y, sv.y, oc.y)
        FILL_ONE(tv.z, sv.z, oc.z)
        FILL_ONE(tv.w, sv.w, oc.w)
#undef FILL_ONE
    }

    float Wreg[D];
#pragma unroll
    for (int k = 0; k < D; k++) Wreg[k] = W[k * D + lane];
    int wave = tid >> 6;
    const int nwaves = FYBLK * 4;
    for (int n = wave; n < N_NODES; n += nwaves) {
        float hv = x[(size_t)n * D + lane] * snorm[n];
        int hb = __float_as_int(hv);
        float p0 = 0.f, p1 = 0.f, p2 = 0.f, p3 = 0.f;
#pragma unroll
        for (int k = 0; k < D; k += 4) {
            p0 = fmaf(__int_as_float(__builtin_amdgcn_readlane(hb, k + 0)), Wreg[k + 0], p0);
            p1 = fmaf(__int_as_float(__builtin_amdgcn_readlane(hb, k + 1)), Wreg[k + 1], p1);
            p2 = fmaf(__int_as_float(__builtin_amdgcn_readlane(hb, k + 2)), Wreg[k + 2], p2);
            p3 = fmaf(__int_as_float(__builtin_amdgcn_readlane(hb, k + 3)), Wreg[k + 3], p3);
        }
        y16[(size_t)n * D + lane] = __float2half((p0 + p1) + (p2 + p3));
    }
}

// Pass 4: out[n] = dnorm[n] * sum_{in-edges} y16[src] + b.
// Pair layout (verified in round 5): even lanes edge i, odd lanes edge i+1;
// each lane loads a __half2 -> one wave-load = 2 rows, 8-deep pipeline = 16
// edges in flight. Combine via shfl(lane^1); coalesced nontemporal stores.
#define GBLK 2048
__global__ __launch_bounds__(256, 8) void gather_kernel(const __half2* __restrict__ y2,
                                                        const int* __restrict__ ssrc,
                                                        const int* __restrict__ base,
                                                        const int* __restrict__ rend,
                                                        const float* __restrict__ dnorm,
                                                        const float* __restrict__ b,
                                                        float* __restrict__ out) {
    int lane = threadIdx.x & 63;
    int half = lane & 1;
    int col  = lane >> 1;
    int wave = (blockIdx.x << 2) | (threadIdx.x >> 6);

    float2 b2 = ((const float2*)b)[col];
    const __half2* yl = y2 + col;   // row stride = 32 half2

    for (int n = wave; n < N_NODES; n += GBLK * 4) {
        int beg = base[n], end = rend[n];
        float ax0 = 0.f, ay0 = 0.f, ax1 = 0.f, ay1 = 0.f;
        float ax2 = 0.f, ay2 = 0.f, ax3 = 0.f, ay3 = 0.f;
        float ax4 = 0.f, ay4 = 0.f, ax5 = 0.f, ay5 = 0.f;
        float ax6 = 0.f, ay6 = 0.f, ax7 = 0.f, ay7 = 0.f;
        int i0 = beg;
        for (; i0 + 16 <= end; i0 += 16) {   // 16 edges, 8 loads in flight
            int e = i0 + half;
            int s0 = ssrc[e],      s1 = ssrc[e + 2],  s2 = ssrc[e + 4],  s3 = ssrc[e + 6];
            int s4 = ssrc[e + 8],  s5 = ssrc[e + 10], s6 = ssrc[e + 12], s7 = ssrc[e + 14];
            float2 f0 = __half22float2(yl[(size_t)s0 * 32]);
            float2 f1 = __half22float2(yl[(size_t)s1 * 32]);
            float2 f2 = __half22float2(yl[(size_t)s2 * 32]);
            float2 f3 = __half22float2(yl[(size_t)s3 * 32]);
            float2 f4 = __half22float2(yl[(size_t)s4 * 32]);
            float2 f5 = __half22float2(yl[(size_t)s5 * 32]);
            float2 f6 = __half22float2(yl[(size_t)s6 * 32]);
            float2 f7 = __half22float2(yl[(size_t)s7 * 32]);
            ax0 += f0.x; ay0 += f0.y; ax1 += f1.x; ay1 += f1.y;
            ax2 += f2.x; ay2 += f2.y; ax3 += f3.x; ay3 += f3.y;
            ax4 += f4.x; ay4 += f4.y; ax5 += f5.x; ay5 += f5.y;
            ax6 += f6.x; ay6 += f6.y; ax7 += f7.x; ay7 += f7.y;
        }
        for (; i0 + 2 <= end; i0 += 2) {     // full pairs
            int s = ssrc[i0 + half];
            float2 f = __half22float2(yl[(size_t)s * 32]);
            ax0 += f.x; ay0 += f.y;
        }
        if (i0 < end && half == 0) {         // odd leftover edge
            int s = ssrc[i0];
            float2 f = __half22float2(yl[(size_t)s * 32]);
            ax1 += f.x; ay1 += f.y;
        }
        float sx = ((ax0 + ax1) + (ax2 + ax3)) + ((ax4 + ax5) + (ax6 + ax7));
        float sy = ((ay0 + ay1) + (ay2 + ay3)) + ((ay4 + ay5) + (ay6 + ay7));
        sx += __shfl(sx, lane ^ 1);
        sy += __shfl(sy, lane ^ 1);
        if (half == 0) {
            float dn = dnorm[n];
            vfloat2 o;
            o.x = fmaf(sx, dn, b2.x);
            o.y = fmaf(sy, dn, b2.y);
            __builtin_nontemporal_store(o, (vfloat2*)(out + (size_t)n * D) + col);
        }
    }
}

extern "C" void kernel_launch(void* const* d_in, const int* in_sizes, int n_in,
                              void* d_out, int out_size, void* d_ws, size_t ws_size,
                              hipStream_t stream) {
    const float* x   = (const float*)d_in[0];
    const int*   src = (const int*)d_in[1];
    const int*   dst = (const int*)d_in[2];
    const float* W   = (const float*)d_in[3];
    const float* b   = (const float*)d_in[4];
    float* out = (float*)d_out;

    char* ws = (char*)d_ws;
    int*          ctr   = (int*)(ws + CTR_OFF);
    int*          base  = (int*)(ws + BASE_OFF);
    int*          rend  = (int*)(ws + END_OFF);
    float*        snorm = (float*)(ws + SNORM_OFF);
    float*        dnorm = (float*)(ws + DNORM_OFF);
    int*          ssrc  = (int*)(ws + SSRC_OFF);
    uchar4*       occ4  = (uchar4*)(ws + OCC_OFF);
    unsigned int* part  = (unsigned int*)(ws + PART_OFF);
    __half*       y16   = (__half*)(ws + Y16_OFF);

    const int4* src4 = (const int4*)src;
    const int4* dst4 = (const int4*)dst;

    degree_occ_kernel<<<2 * SLICES, 256, 0, stream>>>(src4, dst4, part, occ4, ctr);
    merge_scan_kernel<<<(12500 + 255) / 256, 256, 0, stream>>>(part, base, rend,
                                                               snorm, dnorm, ctr);
    filly_kernel<<<FYBLK, 256, 0, stream>>>(src4, dst4, occ4, part, base, ssrc,
                                            x, snorm, W, y16);
    gather_kernel<<<GBLK, 256, 0, stream>>>((const __half2*)y16, ssrc, base, rend,
                                            dnorm, b, out);
}

// Round 8
// 149.892 us; speedup vs baseline: 2.7311x; 1.0105x over previous
//
#include <hip/hip_runtime.h>
#include <hip/hip_fp16.h>

#define N_NODES 50000
#define N_EDGES 800000
#define D 64

#define SLICES 100                 // edge slices per role (src/dst)
#define I4S    2000                // int4 per slice (8000 edges)
#define NI4    200000              // total int4 per role
#define NWORDS 12512               // ceil(50000/4)=12500, padded to /4

typedef float vfloat2 __attribute__((ext_vector_type(2)));

// ---------------------------------------------------------------------------
// Workspace layout (bytes), ~21.2 MB, offsets 256-aligned:
//   [0,        64)         ctr    : int (scan counter; zeroed by degree pass)
//   [256,      200256)     base   : int[N_NODES]
//   [200320,   400320)     rend   : int[N_NODES]
//   [400384,   600384)     snorm  : float[N_NODES]
//   [600448,   800448)     dnorm  : float[N_NODES]
//   [800512,   4000512)    ssrc   : int[N_EDGES]   src ids grouped by dst
//   [4000768,  4800768)    occ    : uchar[N_EDGES] within-slice occurrence
//   [4800768,  14810368)   partial: uint[200][NWORDS] byte hists -> prefixes
//   [14810368, 18010368)   yA     : half[N_NODES*32] features  0..31 (3.2 MB)
//   [18010624, 21210624)   yB     : half[N_NODES*32] features 32..63 (3.2 MB)
// Each y half fits a 4 MB per-XCD L2 — the gather partitions passes by XCD.
// ---------------------------------------------------------------------------
#define CTR_OFF    0
#define BASE_OFF   256
#define END_OFF    200320
#define SNORM_OFF  400384
#define DNORM_OFF  600448
#define SSRC_OFF   800512
#define OCC_OFF    4000768
#define PART_OFF   4800768
#define YA_OFF     14810368
#define YB_OFF     18010624

// ---------------------------------------------------------------------------
// Pass 1: per-slice byte-packed degree histograms in LDS (no fabric atomics).
// dst-role blocks also record each edge's within-slice occurrence byte
// (the atomicAdd return) into occ[] so the fill pass needs no histogram.
// Block b: role = b&1 (0=src/outdeg, 1=dst/indeg), slice = b>>1.
// Block 0 zeroes the scan counter (replaces the memset dispatch).
// ---------------------------------------------------------------------------
__global__ __launch_bounds__(256) void degree_occ_kernel(const int4* __restrict__ src4,
                                                         const int4* __restrict__ dst4,
                                                         unsigned int* __restrict__ partial,
                                                         uchar4* __restrict__ occ4,
                                                         int* __restrict__ ctr) {
    __shared__ unsigned int hist[NWORDS];
    int tid = threadIdx.x;
    if (blockIdx.x == 0 && tid == 0) *ctr = 0;
    uint4* h4 = (uint4*)hist;
    for (int i = tid; i < NWORDS / 4; i += 256) h4[i] = make_uint4(0, 0, 0, 0);
    __syncthreads();

    int role  = blockIdx.x & 1;
    int slice = blockIdx.x >> 1;
    int beg = slice * I4S, end = beg + I4S;
    if (role == 0) {
        for (int i = beg + tid; i < end; i += 256) {
            int4 v = src4[i];
            atomicAdd(&hist[v.x >> 2], 1u << ((v.x & 3) * 8));
            atomicAdd(&hist[v.y >> 2], 1u << ((v.y & 3) * 8));
            atomicAdd(&hist[v.z >> 2], 1u << ((v.z & 3) * 8));
            atomicAdd(&hist[v.w >> 2], 1u << ((v.w & 3) * 8));
        }
    } else {
        for (int i = beg + tid; i < end; i += 256) {
            int4 v = dst4[i];
            unsigned int o0 = (atomicAdd(&hist[v.x >> 2], 1u << ((v.x & 3) * 8)) >> ((v.x & 3) * 8)) & 0xFFu;
            unsigned int o1 = (atomicAdd(&hist[v.y >> 2], 1u << ((v.y & 3) * 8)) >> ((v.y & 3) * 8)) & 0xFFu;
            unsigned int o2 = (atomicAdd(&hist[v.z >> 2], 1u << ((v.z & 3) * 8)) >> ((v.z & 3) * 8)) & 0xFFu;
            unsigned int o3 = (atomicAdd(&hist[v.w >> 2], 1u << ((v.w & 3) * 8)) >> ((v.w & 3) * 8)) & 0xFFu;
            occ4[i] = make_uchar4((unsigned char)o0, (unsigned char)o1,
                                  (unsigned char)o2, (unsigned char)o3);
        }
    }
    __syncthreads();

    uint4* p4 = (uint4*)(partial + (size_t)blockIdx.x * NWORDS);
    for (int i = tid; i < NWORDS / 4; i += 256) p4[i] = h4[i];
}

// Pass 2 (fused merge + scan): thread per word (4 nodes). Sums packed degrees
// over all slices, rewrites dst-role partials in place to per-slice EXCLUSIVE
// prefixes (byte adds; cumulative <= indeg < 255, no carry), then wave-scans
// the 4-node sums for CSR bases; writes node arrays as int4/float4.
__global__ __launch_bounds__(256) void merge_scan_kernel(unsigned int* __restrict__ partial,
                                                         int* __restrict__ base,
                                                         int* __restrict__ rend,
                                                         float* __restrict__ snorm,
                                                         float* __restrict__ dnorm,
                                                         int* __restrict__ ctr) {
    int w = blockIdx.x * blockDim.x + threadIdx.x;
    int lane = threadIdx.x & 63;
    unsigned int accin = 0, accout = 0;
    if (w < 12500) {
        unsigned int* po = partial + w;            // src role: slot 2s
        unsigned int* pd = partial + NWORDS + w;   // dst role: slot 2s+1
#pragma unroll 4
        for (int s = 0; s < SLICES; s++) {
            size_t off = (size_t)(2 * s) * NWORDS;
            accout += po[off];
            unsigned int v = pd[off];
            pd[off] = accin;                       // exclusive prefix before slice s
            accin += v;
        }
    }
    int d0 = accin & 0xFF, d1 = (accin >> 8) & 0xFF,
        d2 = (accin >> 16) & 0xFF, d3 = (accin >> 24) & 0xFF;
    int tsum = d0 + d1 + d2 + d3;
    int run = tsum;  // inclusive wave scan of per-thread totals
#pragma unroll
    for (int off = 1; off < 64; off <<= 1) {
        int v = __shfl_up(run, off);
        if (lane >= off) run += v;
    }
    int wtot = __shfl(run, 63);
    int wbase = 0;
    if (lane == 63) wbase = atomicAdd(ctr, wtot);
    wbase = __shfl(wbase, 63);
    if (w < 12500) {
        int b0 = wbase + run - tsum;
        int b1 = b0 + d0, b2 = b1 + d1, b3 = b2 + d2;
        ((int4*)base)[w] = make_int4(b0, b1, b2, b3);
        ((int4*)rend)[w] = make_int4(b1, b2, b3, b3 + d3);
        ((float4*)dnorm)[w] = make_float4(rsqrtf(fmaxf((float)d0, 1.f)),
                                          rsqrtf(fmaxf((float)d1, 1.f)),
                                          rsqrtf(fmaxf((float)d2, 1.f)),
                                          rsqrtf(fmaxf((float)d3, 1.f)));
        int o0 = accout & 0xFF, o1 = (accout >> 8) & 0xFF,
            o2 = (accout >> 16) & 0xFF, o3 = (accout >> 24) & 0xFF;
        ((float4*)snorm)[w] = make_float4(rsqrtf(fmaxf((float)o0, 1.f)),
                                          rsqrtf(fmaxf((float)o1, 1.f)),
                                          rsqrtf(fmaxf((float)o2, 1.f)),
                                          rsqrtf(fmaxf((float)o3, 1.f)));
    }
}

// Pass 3 (fused fill + y): two independent streaming phases in one dispatch.
// Fill: fully parallel, no LDS, no atomics — p = base[t] + slice prefix + occ.
// Y:    y = (x * snorm) @ W stored fp16, split into two feature-half arrays
//       yA (features 0..31) / yB (32..63), each 3.2 MB (per-XCD-L2-sized).
#define FYBLK 1024
__global__ __launch_bounds__(256, 4) void filly_kernel(const int4* __restrict__ src4,
                                                       const int4* __restrict__ dst4,
                                                       const uchar4* __restrict__ occ4,
                                                       const unsigned int* __restrict__ partial,
                                                       const int* __restrict__ base,
                                                       int* __restrict__ ssrc,
                                                       const float* __restrict__ x,
                                                       const float* __restrict__ snorm,
                                                       const float* __restrict__ W,
                                                       __half* __restrict__ yA,
                                                       __half* __restrict__ yB) {
    int tid = blockIdx.x * blockDim.x + threadIdx.x;
    int lane = threadIdx.x & 63;

    if (tid < NI4) {
        int s = tid / I4S;
        const unsigned int* pref = partial + (size_t)(2 * s + 1) * NWORDS;
        int4 sv = src4[tid], tv = dst4[tid];
        uchar4 oc = occ4[tid];
#define FILL_ONE(T, S, O)                                                     \
        {                                                                     \
            int t = (T); int sh = (t & 3) * 8;                                \
            int p = base[t] + (int)((pref[t >> 2] >> sh) & 0xFFu) + (int)(O); \
            ssrc[p] = (S);                                                    \
        }
        FILL_ONE(tv.x, sv.x, oc.x)
        FILL_ONE(tv.y, sv.y, oc.y)
        FILL_ONE(tv.z, sv.z, oc.z)
        FILL_ONE(tv.w, sv.w, oc.w)
#undef FILL_ONE
    }

    float Wreg[D];
#pragma unroll
    for (int k = 0; k < D; k++) Wreg[k] = W[k * D + lane];
    __half* yh = (lane < 32) ? yA : yB;   // uniform per half-wave
    int jl = lane & 31;
    int wave = tid >> 6;
    const int nwaves = FYBLK * 4;
    for (int n = wave; n < N_NODES; n += nwaves) {
        float hv = x[(size_t)n * D + lane] * snorm[n];
        int hb = __float_as_int(hv);
        float p0 = 0.f, p1 = 0.f, p2 = 0.f, p3 = 0.f;
#pragma unroll
        for (int k = 0; k < D; k += 4) {
            p0 = fmaf(__int_as_float(__builtin_amdgcn_readlane(hb, k + 0)), Wreg[k + 0], p0);
            p1 = fmaf(__int_as_float(__builtin_amdgcn_readlane(hb, k + 1)), Wreg[k + 1], p1);
            p2 = fmaf(__int_as_float(__builtin_amdgcn_readlane(hb, k + 2)), Wreg[k + 2], p2);
            p3 = fmaf(__int_as_float(__builtin_amdgcn_readlane(hb, k + 3)), Wreg[k + 3], p3);
        }
        yh[(size_t)n * 32 + jl] = __float2half((p0 + p1) + (p2 + p3));
    }
}

// Pass 4: out[n] = dnorm[n] * sum_{in-edges} y[src] + b, split by feature half.
// pass = blockIdx&1: with round-robin block->XCD dispatch, even XCDs only read
// yA and odd XCDs only yB — each 3.2 MB array stays resident in its XCDs' 4 MB
// L2, turning the 102 MB of random row reads into L2 hits.
// Lane = (q = edge-in-group-of-4, c = half2 chunk): one wave-load = 4 rows of
// 64 B. shfl ^16/^32 reduce; q==0 writes coalesced nontemporal float2.
#define GBLK 2048
__global__ __launch_bounds__(256, 8) void gather_kernel(const __half2* __restrict__ yA,
                                                        const __half2* __restrict__ yB,
                                                        const int* __restrict__ ssrc,
                                                        const int* __restrict__ base,
                                                        const int* __restrict__ rend,
                                                        const float* __restrict__ dnorm,
                                                        const float* __restrict__ bias,
                                                        float* __restrict__ out) {
    int lane = threadIdx.x & 63;
    int q = lane >> 4;                 // which edge of the group of 4
    int c = lane & 15;                 // half2 chunk: features {2c, 2c+1} of the half
    int pass = blockIdx.x & 1;         // 0 -> yA (features 0..31), 1 -> yB (32..63)
    int pblk = blockIdx.x >> 1;
    int wave = (pblk << 2) | (threadIdx.x >> 6);
    const int nwaves = (GBLK / 2) * 4;

    float2 b2 = ((const float2*)bias)[(pass << 4) + c];
    const __half2* ycol = (pass ? yB : yA) + c;   // row stride = 16 half2

#define ACC(A, F) { (A).x += (F).x; (A).y += (F).y; }

    for (int n = wave; n < N_NODES; n += nwaves) {
        int beg = base[n], end = rend[n];
        float dn = dnorm[n];
        float2 a0 = make_float2(0.f, 0.f), a1 = a0, a2 = a0, a3 = a0;
        int i = beg;
        for (; i + 16 <= end; i += 16) {   // 16 edges, 4 row-group loads in flight
            int s0 = ssrc[i + q],      s1 = ssrc[i + 4 + q];
            int s2 = ssrc[i + 8 + q],  s3 = ssrc[i + 12 + q];
            float2 f0 = __half22float2(ycol[(size_t)s0 * 16]);
            float2 f1 = __half22float2(ycol[(size_t)s1 * 16]);
            float2 f2 = __half22float2(ycol[(size_t)s2 * 16]);
            float2 f3 = __half22float2(ycol[(size_t)s3 * 16]);
            ACC(a0, f0) ACC(a1, f1) ACC(a2, f2) ACC(a3, f3)
        }
        for (; i + 4 <= end; i += 4) {     // 4-edge groups
            int s = ssrc[i + q];
            float2 f = __half22float2(ycol[(size_t)s * 16]);
            ACC(a0, f)
        }
        int rem = end - i;                 // tail < 4 edges
        if (q < rem) {
            int s = ssrc[i + q];
            float2 f = __half22float2(ycol[(size_t)s * 16]);
            ACC(a1, f)
        }
        float2 t;
        t.x = (a0.x + a1.x) + (a2.x + a3.x);
        t.y = (a0.y + a1.y) + (a2.y + a3.y);
        t.x += __shfl(t.x, lane ^ 16); t.y += __shfl(t.y, lane ^ 16);
        t.x += __shfl(t.x, lane ^ 32); t.y += __shfl(t.y, lane ^ 32);
        if (q == 0) {
            vfloat2 o;
            o.x = fmaf(t.x, dn, b2.x);
            o.y = fmaf(t.y, dn, b2.y);
            __builtin_nontemporal_store(o, (vfloat2*)(out + (size_t)n * D + (pass << 5)) + c);
        }
    }
#undef ACC
}

extern "C" void kernel_launch(void* const* d_in, const int* in_sizes, int n_in,
                              void* d_out, int out_size, void* d_ws, size_t ws_size,
                              hipStream_t stream) {
    const float* x   = (const float*)d_in[0];
    const int*   src = (const int*)d_in[1];
    const int*   dst = (const int*)d_in[2];
    const float* W   = (const float*)d_in[3];
    const float* b   = (const float*)d_in[4];
    float* out = (float*)d_out;

    char* ws = (char*)d_ws;
    int*          ctr   = (int*)(ws + CTR_OFF);
    int*          base  = (int*)(ws + BASE_OFF);
    int*          rend  = (int*)(ws + END_OFF);
    float*        snorm = (float*)(ws + SNORM_OFF);
    float*        dnorm = (float*)(ws + DNORM_OFF);
    int*          ssrc  = (int*)(ws + SSRC_OFF);
    uchar4*       occ4  = (uchar4*)(ws + OCC_OFF);
    unsigned int* part  = (unsigned int*)(ws + PART_OFF);
    __half*       yA    = (__half*)(ws + YA_OFF);
    __half*       yB    = (__half*)(ws + YB_OFF);

    const int4* src4 = (const int4*)src;
    const int4* dst4 = (const int4*)dst;

    degree_occ_kernel<<<2 * SLICES, 256, 0, stream>>>(src4, dst4, part, occ4, ctr);
    merge_scan_kernel<<<(12500 + 255) / 256, 256, 0, stream>>>(part, base, rend,
                                                               snorm, dnorm, ctr);
    filly_kernel<<<FYBLK, 256, 0, stream>>>(src4, dst4, occ4, part, base, ssrc,
                                            x, snorm, W, yA, yB);
    gather_kernel<<<GBLK, 256, 0, stream>>>((const __half2*)yA, (const __half2*)yB,
                                            ssrc, base, rend, dnorm, b, out);
}